// Round 4
// baseline (442.356 us; speedup 1.0000x reference)
//
#include <hip/hip_runtime.h>

#define NN 50000
#define NE 1600000
#define DD 64
#define NPB 196          // nodes per bucket
#define NBKT 256         // buckets (NPB*NBKT = 50176 >= NN)
#define S1CAP 1024       // per-(bucket,shard) capacity: lambda=781, +8.7 sigma
#define CSRCAP 8192      // per-bucket CSR capacity: lambda=6250 (+24 sigma, incl. pad4)
#define WS_STRIDE 68     // 128x68 fp32 LDS for W^T in GEMM

static __device__ __forceinline__ unsigned short f2bf(float f) {
    unsigned int u = __float_as_uint(f);
    unsigned int r = (u + 0x7FFFu + ((u >> 16) & 1u)) >> 16;   // RNE
    return (unsigned short)r;
}
static __device__ __forceinline__ float bf2f(unsigned short h) {
    return __uint_as_float((unsigned int)h << 16);
}

// ---------------------------------------------------------------------------
// x (fp32) -> xb (bf16)
// ---------------------------------------------------------------------------
__global__ __launch_bounds__(256) void cast_bf16(
    const float* __restrict__ in, ushort* __restrict__ out, int n4)
{
    int i = blockIdx.x * 256 + threadIdx.x;
    if (i >= n4) return;
    float4 v = ((const float4*)in)[i];
    ushort4 o;
    o.x = f2bf(v.x); o.y = f2bf(v.y); o.z = f2bf(v.z); o.w = f2bf(v.w);
    ((ushort4*)out)[i] = o;
}

// ---------------------------------------------------------------------------
// Stage 1: bin edges into 256 buckets x 8 XCD-shards with SEQUENTIAL cursors.
// Round-3 lesson: per-node slots fail because every line's writes are spread
// over the whole kernel -> partial evictions. Here only the cursor-front line
// of each of 2048 regions is hot (16KB/XCD) -> lines fill monotonically, once.
// Record: .x = dst(16) | w_bf16<<16, .y = node-within-bucket.
// ---------------------------------------------------------------------------
__global__ __launch_bounds__(256) void bin_edges(
    const int* __restrict__ ei, const float* __restrict__ ew,
    int* __restrict__ c1, int2* __restrict__ buf1)
{
    int e = blockIdx.x * 256 + threadIdx.x;   // grid = NE/256 exactly
    int s = ei[e];           // edge_index[0] = src (scatter target)
    int d = ei[NE + e];      // edge_index[1] = dst (gather source)
    float w = ew[e];
    int bkt = s / NPB;
    int sloc = s - bkt * NPB;
    int slot = bkt * 8 + (blockIdx.x & 7);
    int pos = atomicAdd(&c1[slot], 1);
    if (pos < S1CAP)
        buf1[(size_t)slot * S1CAP + pos] =
            make_int2(d | ((int)f2bf(w) << 16), sloc);
}

// ---------------------------------------------------------------------------
// Stage 2: one block per bucket -> dense per-bucket CSR.
// P1 count per node (LDS atomics), block scan (rows padded to 4 records so
// every row start is 16B-aligned for uint4 gathers), P2 place. All CSR writes
// land in this block's private 32KB region -> single-XCD, dense writeback.
// cnt[node] = true degree (nothing is ever dropped at these caps).
// ---------------------------------------------------------------------------
__global__ __launch_bounds__(256) void build_csr(
    const int* __restrict__ c1, const int2* __restrict__ buf1,
    unsigned int* __restrict__ csr, int* __restrict__ rstart,
    int* __restrict__ cnt)
{
    __shared__ int lcnt[NPB];
    __shared__ int lstart[NPB];
    __shared__ int sa[256], sb[256];
    int tid = threadIdx.x, bkt = blockIdx.x;

    if (tid < NPB) lcnt[tid] = 0;
    __syncthreads();

    for (int sh = 0; sh < 8; ++sh) {
        int n = c1[bkt * 8 + sh]; if (n > S1CAP) n = S1CAP;
        const int2* rp = buf1 + (size_t)(bkt * 8 + sh) * S1CAP;
        for (int i = tid; i < n; i += 256)
            atomicAdd(&lcnt[rp[i].y], 1);
    }
    __syncthreads();

    // exclusive scan over ceil4(count): Hillis-Steele, 8 steps
    sa[tid] = (tid < NPB) ? ((lcnt[tid] + 3) & ~3) : 0;
    __syncthreads();
    int* s = sa; int* d = sb;
    for (int off = 1; off < 256; off <<= 1) {
        d[tid] = s[tid] + (tid >= off ? s[tid - off] : 0);
        __syncthreads();
        int* t = s; s = d; d = t;
    }
    if (tid < NPB) {
        int ex = (tid == 0) ? 0 : s[tid - 1];
        lstart[tid] = ex;
        int node = bkt * NPB + tid;
        if (node < NN) {
            rstart[node] = bkt * CSRCAP + ex;
            cnt[node] = lcnt[tid];
        }
    }
    __syncthreads();
    if (tid < NPB) lcnt[tid] = 0;   // reuse as placement cursor
    __syncthreads();

    for (int sh = 0; sh < 8; ++sh) {
        int n = c1[bkt * 8 + sh]; if (n > S1CAP) n = S1CAP;
        const int2* rp = buf1 + (size_t)(bkt * 8 + sh) * S1CAP;
        for (int i = tid; i < n; i += 256) {
            int2 r = rp[i];
            int pos = atomicAdd(&lcnt[r.y], 1);
            csr[bkt * CSRCAP + lstart[r.y] + pos] = (unsigned int)r.x;
        }
    }
}

// ---------------------------------------------------------------------------
// Scatter-mean as gather: one wave per node (50K independent waves), lane =
// feature, register acc. ONE contiguous CSR run per node + 8-deep unroll ->
// 8 outstanding 128B gathers per wave (the Round-3 MLP fix).
// ---------------------------------------------------------------------------
__global__ __launch_bounds__(256) void aggregate(
    const ushort* __restrict__ feat, const int* __restrict__ rstart,
    const int* __restrict__ cnt, const unsigned int* __restrict__ csr,
    ushort* __restrict__ aggb)
{
    int node = (blockIdx.x * 256 + threadIdx.x) >> 6;   // grid exact: node < NN
    int lane = threadIdx.x & 63;
    int n = cnt[node];
    const unsigned int* __restrict__ rp = csr + rstart[node];
    float acc = 0.f;
    int i = 0;
    for (; i + 8 <= n; i += 8) {
        uint4 ra = *(const uint4*)(rp + i);
        uint4 rb = *(const uint4*)(rp + i + 4);
        float v0 = bf2f(feat[(ra.x & 0xFFFF) * DD + lane]);
        float v1 = bf2f(feat[(ra.y & 0xFFFF) * DD + lane]);
        float v2 = bf2f(feat[(ra.z & 0xFFFF) * DD + lane]);
        float v3 = bf2f(feat[(ra.w & 0xFFFF) * DD + lane]);
        float v4 = bf2f(feat[(rb.x & 0xFFFF) * DD + lane]);
        float v5 = bf2f(feat[(rb.y & 0xFFFF) * DD + lane]);
        float v6 = bf2f(feat[(rb.z & 0xFFFF) * DD + lane]);
        float v7 = bf2f(feat[(rb.w & 0xFFFF) * DD + lane]);
        acc += bf2f((unsigned short)(ra.x >> 16)) * v0;
        acc += bf2f((unsigned short)(ra.y >> 16)) * v1;
        acc += bf2f((unsigned short)(ra.z >> 16)) * v2;
        acc += bf2f((unsigned short)(ra.w >> 16)) * v3;
        acc += bf2f((unsigned short)(rb.x >> 16)) * v4;
        acc += bf2f((unsigned short)(rb.y >> 16)) * v5;
        acc += bf2f((unsigned short)(rb.z >> 16)) * v6;
        acc += bf2f((unsigned short)(rb.w >> 16)) * v7;
    }
    for (; i + 4 <= n; i += 4) {
        uint4 ra = *(const uint4*)(rp + i);
        float v0 = bf2f(feat[(ra.x & 0xFFFF) * DD + lane]);
        float v1 = bf2f(feat[(ra.y & 0xFFFF) * DD + lane]);
        float v2 = bf2f(feat[(ra.z & 0xFFFF) * DD + lane]);
        float v3 = bf2f(feat[(ra.w & 0xFFFF) * DD + lane]);
        acc += bf2f((unsigned short)(ra.x >> 16)) * v0;
        acc += bf2f((unsigned short)(ra.y >> 16)) * v1;
        acc += bf2f((unsigned short)(ra.z >> 16)) * v2;
        acc += bf2f((unsigned short)(ra.w >> 16)) * v3;
    }
    for (; i < n; ++i) {
        unsigned int r = rp[i];
        acc += bf2f((unsigned short)(r >> 16)) * bf2f(feat[(r & 0xFFFF) * DD + lane]);
    }
    float dm = (float)(n > 1 ? n : 1);
    aggb[(size_t)node * DD + lane] = f2bf(acc / dm);
}

// ---------------------------------------------------------------------------
// out[n][j] = relu( b[j] + X[n][:]·W[j][0:64] + A[n][:]·W[j][64:128] )
// X, A bf16; W^T in LDS; 4x4 fp32 micro-tile per thread.
// ---------------------------------------------------------------------------
__global__ __launch_bounds__(256) void sage_gemm_relu(
    const ushort* __restrict__ X, const ushort* __restrict__ A,
    const float* __restrict__ W, const float* __restrict__ bias,
    float* __restrict__ out, ushort* __restrict__ outb)
{
    __shared__ float Ws[128 * WS_STRIDE];
    int tid = threadIdx.x;
    int nb = blockIdx.x * 64;

    for (int idx = tid; idx < 8192; idx += 256) {
        int j = idx >> 7;
        int k = idx & 127;
        Ws[k * WS_STRIDE + j] = W[idx];
    }
    __syncthreads();

    int tx = tid & 15;
    int ty = tid >> 4;

    int r[4];
#pragma unroll
    for (int i = 0; i < 4; ++i) {
        int row = nb + ty * 4 + i;
        r[i] = row < NN ? row : NN - 1;
    }

    float acc[4][4];
#pragma unroll
    for (int i = 0; i < 4; ++i)
#pragma unroll
        for (int j = 0; j < 4; ++j) acc[i][j] = 0.f;

#pragma unroll 4
    for (int k4 = 0; k4 < 16; ++k4) {
        float4 a[4], w[4];
#pragma unroll
        for (int i = 0; i < 4; ++i) {
            ushort4 u = *(const ushort4*)&X[r[i] * 64 + k4 * 4];
            a[i] = make_float4(bf2f(u.x), bf2f(u.y), bf2f(u.z), bf2f(u.w));
        }
#pragma unroll
        for (int kk = 0; kk < 4; ++kk)
            w[kk] = *(const float4*)&Ws[(k4 * 4 + kk) * WS_STRIDE + tx * 4];
#pragma unroll
        for (int i = 0; i < 4; ++i) {
            acc[i][0] += a[i].x * w[0].x + a[i].y * w[1].x + a[i].z * w[2].x + a[i].w * w[3].x;
            acc[i][1] += a[i].x * w[0].y + a[i].y * w[1].y + a[i].z * w[2].y + a[i].w * w[3].y;
            acc[i][2] += a[i].x * w[0].z + a[i].y * w[1].z + a[i].z * w[2].z + a[i].w * w[3].z;
            acc[i][3] += a[i].x * w[0].w + a[i].y * w[1].w + a[i].z * w[2].w + a[i].w * w[3].w;
        }
    }
#pragma unroll 4
    for (int k4 = 0; k4 < 16; ++k4) {
        float4 a[4], w[4];
#pragma unroll
        for (int i = 0; i < 4; ++i) {
            ushort4 u = *(const ushort4*)&A[r[i] * 64 + k4 * 4];
            a[i] = make_float4(bf2f(u.x), bf2f(u.y), bf2f(u.z), bf2f(u.w));
        }
#pragma unroll
        for (int kk = 0; kk < 4; ++kk)
            w[kk] = *(const float4*)&Ws[(64 + k4 * 4 + kk) * WS_STRIDE + tx * 4];
#pragma unroll
        for (int i = 0; i < 4; ++i) {
            acc[i][0] += a[i].x * w[0].x + a[i].y * w[1].x + a[i].z * w[2].x + a[i].w * w[3].x;
            acc[i][1] += a[i].x * w[0].y + a[i].y * w[1].y + a[i].z * w[2].y + a[i].w * w[3].y;
            acc[i][2] += a[i].x * w[0].z + a[i].y * w[1].z + a[i].z * w[2].z + a[i].w * w[3].z;
            acc[i][3] += a[i].x * w[0].w + a[i].y * w[1].w + a[i].z * w[2].w + a[i].w * w[3].w;
        }
    }

    float4 bb = *(const float4*)&bias[tx * 4];
#pragma unroll
    for (int i = 0; i < 4; ++i) {
        int n = nb + ty * 4 + i;
        if (n < NN) {
            float4 o;
            o.x = fmaxf(acc[i][0] + bb.x, 0.f);
            o.y = fmaxf(acc[i][1] + bb.y, 0.f);
            o.z = fmaxf(acc[i][2] + bb.z, 0.f);
            o.w = fmaxf(acc[i][3] + bb.w, 0.f);
            if (out) *(float4*)&out[n * 64 + tx * 4] = o;
            if (outb) {
                ushort4 ob;
                ob.x = f2bf(o.x); ob.y = f2bf(o.y); ob.z = f2bf(o.z); ob.w = f2bf(o.w);
                *(ushort4*)&outb[n * 64 + tx * 4] = ob;
            }
        }
    }
}

// ---------------------------------------------------------------------------
extern "C" void kernel_launch(void* const* d_in, const int* in_sizes, int n_in,
                              void* d_out, int out_size, void* d_ws, size_t ws_size,
                              hipStream_t stream)
{
    const float* x  = (const float*)d_in[0];
    const int*   ei = (const int*)d_in[1];
    const float* ew = (const float*)d_in[2];
    const float* W1 = (const float*)d_in[3];
    const float* b1 = (const float*)d_in[4];
    const float* W2 = (const float*)d_in[5];
    const float* b2 = (const float*)d_in[6];
    float* out = (float*)d_out;

    // workspace layout, ~44.8 MB (16B-aligned offsets)
    char* ws = (char*)d_ws;
    int*          c1     = (int*)ws;                          //     8,192 B (pad 16K)
    int2*         buf1   = (int2*)(ws + 16384);               // 16,777,216 B
    unsigned int* csr    = (unsigned int*)(ws + 16793600);    //  8,388,608 B
    int*          rstart = (int*)(ws + 25182208);             //    200,064 B
    int*          cnt    = (int*)(ws + 25382272);             //    200,064 B
    ushort*       xb     = (ushort*)(ws + 25582336);          //  6,400,000 B
    ushort*       aggb   = (ushort*)(ws + 31982336);          //  6,400,000 B
    ushort*       h1b    = (ushort*)(ws + 38382336);          //  6,400,000 B

    hipMemsetAsync(c1, 0, NBKT * 8 * sizeof(int), stream);

    cast_bf16<<<(NN * DD / 4) / 256, 256, 0, stream>>>(x, xb, NN * DD / 4);
    bin_edges<<<NE / 256, 256, 0, stream>>>(ei, ew, c1, buf1);
    build_csr<<<NBKT, 256, 0, stream>>>(c1, buf1, csr, rstart, cnt);

    // layer 1
    aggregate<<<(NN * 64) / 256, 256, 0, stream>>>(xb, rstart, cnt, csr, aggb);
    sage_gemm_relu<<<(NN + 63) / 64, 256, 0, stream>>>(xb, aggb, W1, b1, nullptr, h1b);

    // layer 2 (same graph, reuse CSR)
    aggregate<<<(NN * 64) / 256, 256, 0, stream>>>(h1b, rstart, cnt, csr, aggb);
    sage_gemm_relu<<<(NN + 63) / 64, 256, 0, stream>>>(h1b, aggb, W2, b2, out, nullptr);
}

// Round 6
// 251.802 us; speedup vs baseline: 1.7568x; 1.7568x over previous
//
#include <hip/hip_runtime.h>

#define NN 50000
#define NE 1600000
#define DD 64
#define NPB 196          // nodes per bucket
#define NBKT 256         // buckets (NPB*NBKT = 50176 >= NN)
#define CHUNK 2500       // edges per bin block (640 blocks * 2500 = NE)
#define NBLK 640
#define SLOT 24          // LDS records per bucket: lambda=9.77, +4.5 sigma
#define S1CAP 1024       // per-(bucket,shard) region: lambda=781, +8.7 sigma
#define SPCAP 512        // per-bucket global spill region
#define CSRCAP 8192      // per-bucket CSR capacity (R4-proven)
#define WS_STRIDE 68     // 128x68 fp32 LDS for W^T in GEMM

static __device__ __forceinline__ unsigned short f2bf(float f) {
    unsigned int u = __float_as_uint(f);
    unsigned int r = (u + 0x7FFFu + ((u >> 16) & 1u)) >> 16;   // RNE
    return (unsigned short)r;
}
static __device__ __forceinline__ float bf2f(unsigned short h) {
    return __uint_as_float((unsigned int)h << 16);
}

// ---------------------------------------------------------------------------
// x (fp32) -> xb (bf16)
// ---------------------------------------------------------------------------
__global__ __launch_bounds__(256) void cast_bf16(
    const float* __restrict__ in, ushort* __restrict__ out, int n4)
{
    int i = blockIdx.x * 256 + threadIdx.x;
    if (i >= n4) return;
    float4 v = ((const float4*)in)[i];
    ushort4 o;
    o.x = f2bf(v.x); o.y = f2bf(v.y); o.z = f2bf(v.z); o.w = f2bf(v.w);
    ((ushort4*)out)[i] = o;
}

// ---------------------------------------------------------------------------
// LDS-staged binning (R1/R3/R4 lesson: ONE GLOBAL ATOMIC PER EDGE = 120+ us,
// no matter the counter layout). Per block: bin 2500 edges into LDS buckets
// with LDS fetch-adds, then ONE global cursor atomic per (block,bucket)
// (164K total, 10x fewer) + wave-cooperative contiguous burst copy into the
// (bucket, blockIdx&7) region. R5 BUG FIX: block has 4 waves -> each wave
// flushes NBKT/4=64 buckets (R5 covered only 128/256 buckets -> poison reads).
// Record: .x = dst(16) | w_bf16<<16, .y = node-within-bucket.
// ---------------------------------------------------------------------------
__global__ __launch_bounds__(256) void bin_lds(
    const int* __restrict__ ei, const float* __restrict__ ew,
    int* __restrict__ gcur, int* __restrict__ gspillc,
    int2* __restrict__ buf1, int2* __restrict__ spill)
{
    __shared__ int2 slot[NBKT * SLOT];   // 48 KB
    __shared__ int  lcnt[NBKT];
    __shared__ int  lbase[NBKT];
    int tid = threadIdx.x;
    int shard = blockIdx.x & 7;

    for (int b = tid; b < NBKT; b += 256) lcnt[b] = 0;
    __syncthreads();

    int e0 = blockIdx.x * CHUNK;
    for (int i = tid; i < CHUNK; i += 256) {
        int e = e0 + i;
        int s = ei[e];           // edge_index[0] = src (scatter target)
        int d = ei[NE + e];      // edge_index[1] = dst (gather source)
        float w = ew[e];
        int bkt = s / NPB;
        int sloc = s - bkt * NPB;
        int2 rec = make_int2(d | ((int)f2bf(w) << 16), sloc);
        int pos = atomicAdd(&lcnt[bkt], 1);
        if (pos < SLOT) {
            slot[bkt * SLOT + pos] = rec;
        } else {
            int sp = atomicAdd(&gspillc[bkt], 1);
            if (sp < SPCAP) spill[bkt * SPCAP + sp] = rec;
        }
    }
    __syncthreads();

    // one global reservation per (block,bucket); tid==bucket (256==NBKT)
    {
        int b = tid;
        int n = lcnt[b]; if (n > SLOT) n = SLOT;
        lcnt[b] = n;
        lbase[b] = (n > 0) ? atomicAdd(&gcur[b * 8 + shard], n) : 0;
    }
    __syncthreads();

    // wave-cooperative contiguous burst copy: wave w flushes buckets w*64..+63
    int wave = tid >> 6, lane = tid & 63;
    for (int j = 0; j < NBKT / 4; ++j) {
        int b = wave * (NBKT / 4) + j;
        int n = lcnt[b];
        int base = lbase[b];
        for (int i = lane; i < n; i += 64) {
            int p = base + i;
            int2 rec = slot[b * SLOT + i];
            if (p < S1CAP) {
                buf1[((size_t)b * 8 + shard) * S1CAP + p] = rec;
            } else {
                int sp = atomicAdd(&gspillc[b], 1);
                if (sp < SPCAP) spill[b * SPCAP + sp] = rec;
            }
        }
    }
}

// ---------------------------------------------------------------------------
// One block per bucket -> dense per-bucket CSR. Count (LDS atomics) ->
// block scan (rows ceil4-padded so row starts are 16B-aligned) -> place.
// Consumes 8 shard runs + the spill run. cnt[node] = true degree.
// ---------------------------------------------------------------------------
__global__ __launch_bounds__(256) void build_csr(
    const int* __restrict__ gcur, const int2* __restrict__ buf1,
    const int* __restrict__ gspillc, const int2* __restrict__ spill,
    unsigned int* __restrict__ csr, int* __restrict__ rstart,
    int* __restrict__ cnt)
{
    __shared__ int lcnt[NPB];
    __shared__ int lstart[NPB];
    __shared__ int sa[256], sb[256];
    int tid = threadIdx.x, bkt = blockIdx.x;

    if (tid < NPB) lcnt[tid] = 0;
    __syncthreads();

    for (int sh = 0; sh < 9; ++sh) {
        int n; const int2* rp;
        if (sh < 8) {
            n = gcur[bkt * 8 + sh]; if (n > S1CAP) n = S1CAP;
            rp = buf1 + ((size_t)bkt * 8 + sh) * S1CAP;
        } else {
            n = gspillc[bkt]; if (n > SPCAP) n = SPCAP;
            rp = spill + (size_t)bkt * SPCAP;
        }
        for (int i = tid; i < n; i += 256)
            atomicAdd(&lcnt[rp[i].y], 1);
    }
    __syncthreads();

    // exclusive scan over ceil4(count): Hillis-Steele, 8 steps
    sa[tid] = (tid < NPB) ? ((lcnt[tid] + 3) & ~3) : 0;
    __syncthreads();
    int* s = sa; int* d = sb;
    for (int off = 1; off < 256; off <<= 1) {
        d[tid] = s[tid] + (tid >= off ? s[tid - off] : 0);
        __syncthreads();
        int* t = s; s = d; d = t;
    }
    if (tid < NPB) {
        int ex = (tid == 0) ? 0 : s[tid - 1];
        lstart[tid] = ex;
        int node = bkt * NPB + tid;
        if (node < NN) {
            rstart[node] = bkt * CSRCAP + ex;
            cnt[node] = lcnt[tid];
        }
    }
    __syncthreads();
    if (tid < NPB) lcnt[tid] = 0;   // reuse as placement cursor
    __syncthreads();

    for (int sh = 0; sh < 9; ++sh) {
        int n; const int2* rp;
        if (sh < 8) {
            n = gcur[bkt * 8 + sh]; if (n > S1CAP) n = S1CAP;
            rp = buf1 + ((size_t)bkt * 8 + sh) * S1CAP;
        } else {
            n = gspillc[bkt]; if (n > SPCAP) n = SPCAP;
            rp = spill + (size_t)bkt * SPCAP;
        }
        for (int i = tid; i < n; i += 256) {
            int2 r = rp[i];
            int pos = atomicAdd(&lcnt[r.y], 1);
            csr[bkt * CSRCAP + lstart[r.y] + pos] = (unsigned int)r.x;
        }
    }
}

// ---------------------------------------------------------------------------
// Scatter-mean as gather: one wave per node (50K independent waves), lane =
// feature, register acc, contiguous CSR run, 8-deep gather unroll.
// ---------------------------------------------------------------------------
__global__ __launch_bounds__(256) void aggregate(
    const ushort* __restrict__ feat, const int* __restrict__ rstart,
    const int* __restrict__ cnt, const unsigned int* __restrict__ csr,
    ushort* __restrict__ aggb)
{
    int node = (blockIdx.x * 256 + threadIdx.x) >> 6;   // grid exact: node < NN
    int lane = threadIdx.x & 63;
    int n = cnt[node];
    const unsigned int* __restrict__ rp = csr + rstart[node];
    float acc = 0.f;
    int i = 0;
    for (; i + 8 <= n; i += 8) {
        uint4 ra = *(const uint4*)(rp + i);
        uint4 rb = *(const uint4*)(rp + i + 4);
        float v0 = bf2f(feat[(ra.x & 0xFFFF) * DD + lane]);
        float v1 = bf2f(feat[(ra.y & 0xFFFF) * DD + lane]);
        float v2 = bf2f(feat[(ra.z & 0xFFFF) * DD + lane]);
        float v3 = bf2f(feat[(ra.w & 0xFFFF) * DD + lane]);
        float v4 = bf2f(feat[(rb.x & 0xFFFF) * DD + lane]);
        float v5 = bf2f(feat[(rb.y & 0xFFFF) * DD + lane]);
        float v6 = bf2f(feat[(rb.z & 0xFFFF) * DD + lane]);
        float v7 = bf2f(feat[(rb.w & 0xFFFF) * DD + lane]);
        acc += bf2f((unsigned short)(ra.x >> 16)) * v0;
        acc += bf2f((unsigned short)(ra.y >> 16)) * v1;
        acc += bf2f((unsigned short)(ra.z >> 16)) * v2;
        acc += bf2f((unsigned short)(ra.w >> 16)) * v3;
        acc += bf2f((unsigned short)(rb.x >> 16)) * v4;
        acc += bf2f((unsigned short)(rb.y >> 16)) * v5;
        acc += bf2f((unsigned short)(rb.z >> 16)) * v6;
        acc += bf2f((unsigned short)(rb.w >> 16)) * v7;
    }
    for (; i + 4 <= n; i += 4) {
        uint4 ra = *(const uint4*)(rp + i);
        float v0 = bf2f(feat[(ra.x & 0xFFFF) * DD + lane]);
        float v1 = bf2f(feat[(ra.y & 0xFFFF) * DD + lane]);
        float v2 = bf2f(feat[(ra.z & 0xFFFF) * DD + lane]);
        float v3 = bf2f(feat[(ra.w & 0xFFFF) * DD + lane]);
        acc += bf2f((unsigned short)(ra.x >> 16)) * v0;
        acc += bf2f((unsigned short)(ra.y >> 16)) * v1;
        acc += bf2f((unsigned short)(ra.z >> 16)) * v2;
        acc += bf2f((unsigned short)(ra.w >> 16)) * v3;
    }
    for (; i < n; ++i) {
        unsigned int r = rp[i];
        acc += bf2f((unsigned short)(r >> 16)) * bf2f(feat[(r & 0xFFFF) * DD + lane]);
    }
    float dm = (float)(n > 1 ? n : 1);
    aggb[(size_t)node * DD + lane] = f2bf(acc / dm);
}

// ---------------------------------------------------------------------------
// out[n][j] = relu( b[j] + X[n][:]·W[j][0:64] + A[n][:]·W[j][64:128] )
// X, A bf16; W^T in LDS; 4x4 fp32 micro-tile per thread.
// ---------------------------------------------------------------------------
__global__ __launch_bounds__(256) void sage_gemm_relu(
    const ushort* __restrict__ X, const ushort* __restrict__ A,
    const float* __restrict__ W, const float* __restrict__ bias,
    float* __restrict__ out, ushort* __restrict__ outb)
{
    __shared__ float Ws[128 * WS_STRIDE];
    int tid = threadIdx.x;
    int nb = blockIdx.x * 64;

    for (int idx = tid; idx < 8192; idx += 256) {
        int j = idx >> 7;
        int k = idx & 127;
        Ws[k * WS_STRIDE + j] = W[idx];
    }
    __syncthreads();

    int tx = tid & 15;
    int ty = tid >> 4;

    int r[4];
#pragma unroll
    for (int i = 0; i < 4; ++i) {
        int row = nb + ty * 4 + i;
        r[i] = row < NN ? row : NN - 1;
    }

    float acc[4][4];
#pragma unroll
    for (int i = 0; i < 4; ++i)
#pragma unroll
        for (int j = 0; j < 4; ++j) acc[i][j] = 0.f;

#pragma unroll 4
    for (int k4 = 0; k4 < 16; ++k4) {
        float4 a[4], w[4];
#pragma unroll
        for (int i = 0; i < 4; ++i) {
            ushort4 u = *(const ushort4*)&X[r[i] * 64 + k4 * 4];
            a[i] = make_float4(bf2f(u.x), bf2f(u.y), bf2f(u.z), bf2f(u.w));
        }
#pragma unroll
        for (int kk = 0; kk < 4; ++kk)
            w[kk] = *(const float4*)&Ws[(k4 * 4 + kk) * WS_STRIDE + tx * 4];
#pragma unroll
        for (int i = 0; i < 4; ++i) {
            acc[i][0] += a[i].x * w[0].x + a[i].y * w[1].x + a[i].z * w[2].x + a[i].w * w[3].x;
            acc[i][1] += a[i].x * w[0].y + a[i].y * w[1].y + a[i].z * w[2].y + a[i].w * w[3].y;
            acc[i][2] += a[i].x * w[0].z + a[i].y * w[1].z + a[i].z * w[2].z + a[i].w * w[3].z;
            acc[i][3] += a[i].x * w[0].w + a[i].y * w[1].w + a[i].z * w[2].w + a[i].w * w[3].w;
        }
    }
#pragma unroll 4
    for (int k4 = 0; k4 < 16; ++k4) {
        float4 a[4], w[4];
#pragma unroll
        for (int i = 0; i < 4; ++i) {
            ushort4 u = *(const ushort4*)&A[r[i] * 64 + k4 * 4];
            a[i] = make_float4(bf2f(u.x), bf2f(u.y), bf2f(u.z), bf2f(u.w));
        }
#pragma unroll
        for (int kk = 0; kk < 4; ++kk)
            w[kk] = *(const float4*)&Ws[(64 + k4 * 4 + kk) * WS_STRIDE + tx * 4];
#pragma unroll
        for (int i = 0; i < 4; ++i) {
            acc[i][0] += a[i].x * w[0].x + a[i].y * w[1].x + a[i].z * w[2].x + a[i].w * w[3].x;
            acc[i][1] += a[i].x * w[0].y + a[i].y * w[1].y + a[i].z * w[2].y + a[i].w * w[3].y;
            acc[i][2] += a[i].x * w[0].z + a[i].y * w[1].z + a[i].z * w[2].z + a[i].w * w[3].z;
            acc[i][3] += a[i].x * w[0].w + a[i].y * w[1].w + a[i].z * w[2].w + a[i].w * w[3].w;
        }
    }

    float4 bb = *(const float4*)&bias[tx * 4];
#pragma unroll
    for (int i = 0; i < 4; ++i) {
        int n = nb + ty * 4 + i;
        if (n < NN) {
            float4 o;
            o.x = fmaxf(acc[i][0] + bb.x, 0.f);
            o.y = fmaxf(acc[i][1] + bb.y, 0.f);
            o.z = fmaxf(acc[i][2] + bb.z, 0.f);
            o.w = fmaxf(acc[i][3] + bb.w, 0.f);
            if (out) *(float4*)&out[n * 64 + tx * 4] = o;
            if (outb) {
                ushort4 ob;
                ob.x = f2bf(o.x); ob.y = f2bf(o.y); ob.z = f2bf(o.z); ob.w = f2bf(o.w);
                *(ushort4*)&outb[n * 64 + tx * 4] = ob;
            }
        }
    }
}

// ---------------------------------------------------------------------------
extern "C" void kernel_launch(void* const* d_in, const int* in_sizes, int n_in,
                              void* d_out, int out_size, void* d_ws, size_t ws_size,
                              hipStream_t stream)
{
    const float* x  = (const float*)d_in[0];
    const int*   ei = (const int*)d_in[1];
    const float* ew = (const float*)d_in[2];
    const float* W1 = (const float*)d_in[3];
    const float* b1 = (const float*)d_in[4];
    const float* W2 = (const float*)d_in[5];
    const float* b2 = (const float*)d_in[6];
    float* out = (float*)d_out;

    // workspace layout, ~45.8 MB (16B-aligned offsets)
    char* ws = (char*)d_ws;
    int*          gcur    = (int*)ws;                          //      8,192 B
    int*          gspillc = (int*)(ws + 8192);                 //      1,024 B
    int2*         buf1    = (int2*)(ws + 16384);               // 16,777,216 B
    int2*         spill   = (int2*)(ws + 16793600);            //  1,048,576 B
    unsigned int* csr     = (unsigned int*)(ws + 17842176);    //  8,388,608 B
    int*          rstart  = (int*)(ws + 26230784);             //    200,704 B
    int*          cnt     = (int*)(ws + 26431488);             //    200,704 B
    ushort*       xb      = (ushort*)(ws + 26632192);          //  6,400,000 B
    ushort*       aggb    = (ushort*)(ws + 33032192);          //  6,400,000 B
    ushort*       h1b     = (ushort*)(ws + 39432192);          //  6,400,000 B

    hipMemsetAsync(gcur, 0, 9216, stream);   // gcur + gspillc

    cast_bf16<<<(NN * DD / 4) / 256, 256, 0, stream>>>(x, xb, NN * DD / 4);
    bin_lds<<<NBLK, 256, 0, stream>>>(ei, ew, gcur, gspillc, buf1, spill);
    build_csr<<<NBKT, 256, 0, stream>>>(gcur, buf1, gspillc, spill, csr, rstart, cnt);

    // layer 1
    aggregate<<<(NN * 64) / 256, 256, 0, stream>>>(xb, rstart, cnt, csr, aggb);
    sage_gemm_relu<<<(NN + 63) / 64, 256, 0, stream>>>(xb, aggb, W1, b1, nullptr, h1b);

    // layer 2 (same graph, reuse CSR)
    aggregate<<<(NN * 64) / 256, 256, 0, stream>>>(h1b, rstart, cnt, csr, aggb);
    sage_gemm_relu<<<(NN + 63) / 64, 256, 0, stream>>>(h1b, aggb, W2, b2, out, nullptr);
}

// Round 7
// 231.584 us; speedup vs baseline: 1.9101x; 1.0873x over previous
//
#include <hip/hip_runtime.h>

#define NN 50000
#define NE 1600000
#define DD 64
#define NPB 196          // nodes per bucket
#define NBKT 256         // buckets (NPB*NBKT = 50176 >= NN)
#define CHUNK 2500       // edges per bin block (640 blocks * 2500 = NE)
#define NBLK 640
#define SLOT 24          // LDS records per bucket: lambda=9.77, +4.5 sigma
#define S1CAP 1024       // per-(bucket,shard) region: lambda=781, +8.7 sigma
#define SPCAP 512        // per-bucket global spill region
#define CSRCAP 8192      // per-bucket CSR capacity (R4-proven)

typedef __attribute__((ext_vector_type(8))) short bf16x8;   // 8 bf16 = 4 VGPR
typedef __attribute__((ext_vector_type(4))) float f32x4;

static __device__ __forceinline__ unsigned short f2bf(float f) {
    unsigned int u = __float_as_uint(f);
    unsigned int r = (u + 0x7FFFu + ((u >> 16) & 1u)) >> 16;   // RNE
    return (unsigned short)r;
}
static __device__ __forceinline__ float bf2f(unsigned short h) {
    return __uint_as_float((unsigned int)h << 16);
}

// ---------------------------------------------------------------------------
// x (fp32) -> xb (bf16)
// ---------------------------------------------------------------------------
__global__ __launch_bounds__(256) void cast_bf16(
    const float* __restrict__ in, ushort* __restrict__ out, int n4)
{
    int i = blockIdx.x * 256 + threadIdx.x;
    if (i >= n4) return;
    float4 v = ((const float4*)in)[i];
    ushort4 o;
    o.x = f2bf(v.x); o.y = f2bf(v.y); o.z = f2bf(v.z); o.w = f2bf(v.w);
    ((ushort4*)out)[i] = o;
}

// W1,W2 (64x128 fp32) -> bf16 copies for MFMA B-operand
__global__ __launch_bounds__(256) void cast_w(
    const float* __restrict__ W1, const float* __restrict__ W2,
    ushort* __restrict__ W1b, ushort* __restrict__ W2b)
{
    int i = blockIdx.x * 256 + threadIdx.x;   // 16 blocks = 4096 threads
    const float* src = (i < 2048) ? W1 : W2;
    ushort* dst = (i < 2048) ? W1b : W2b;
    int j = i & 2047;
    float4 v = ((const float4*)src)[j];
    ushort4 o;
    o.x = f2bf(v.x); o.y = f2bf(v.y); o.z = f2bf(v.z); o.w = f2bf(v.w);
    ((ushort4*)dst)[j] = o;
}

// ---------------------------------------------------------------------------
// LDS-staged binning (R6-proven: one global atomic per (block,bucket), not
// per edge). Burst-flush into (bucket, blockIdx&7) sequential regions.
// Record: .x = dst(16) | w_bf16<<16, .y = node-within-bucket.
// ---------------------------------------------------------------------------
__global__ __launch_bounds__(256) void bin_lds(
    const int* __restrict__ ei, const float* __restrict__ ew,
    int* __restrict__ gcur, int* __restrict__ gspillc,
    int2* __restrict__ buf1, int2* __restrict__ spill)
{
    __shared__ int2 slot[NBKT * SLOT];   // 48 KB
    __shared__ int  lcnt[NBKT];
    __shared__ int  lbase[NBKT];
    int tid = threadIdx.x;
    int shard = blockIdx.x & 7;

    for (int b = tid; b < NBKT; b += 256) lcnt[b] = 0;
    __syncthreads();

    int e0 = blockIdx.x * CHUNK;
    for (int i = tid; i < CHUNK; i += 256) {
        int e = e0 + i;
        int s = ei[e];           // edge_index[0] = src (scatter target)
        int d = ei[NE + e];      // edge_index[1] = dst (gather source)
        float w = ew[e];
        int bkt = s / NPB;
        int sloc = s - bkt * NPB;
        int2 rec = make_int2(d | ((int)f2bf(w) << 16), sloc);
        int pos = atomicAdd(&lcnt[bkt], 1);
        if (pos < SLOT) {
            slot[bkt * SLOT + pos] = rec;
        } else {
            int sp = atomicAdd(&gspillc[bkt], 1);
            if (sp < SPCAP) spill[bkt * SPCAP + sp] = rec;
        }
    }
    __syncthreads();

    // one global reservation per (block,bucket); tid==bucket (256==NBKT)
    {
        int b = tid;
        int n = lcnt[b]; if (n > SLOT) n = SLOT;
        lcnt[b] = n;
        lbase[b] = (n > 0) ? atomicAdd(&gcur[b * 8 + shard], n) : 0;
    }
    __syncthreads();

    // wave-cooperative burst copy: wave w flushes buckets w*64..+63
    int wave = tid >> 6, lane = tid & 63;
    for (int j = 0; j < NBKT / 4; ++j) {
        int b = wave * (NBKT / 4) + j;
        int n = lcnt[b];
        int base = lbase[b];
        for (int i = lane; i < n; i += 64) {
            int p = base + i;
            int2 rec = slot[b * SLOT + i];
            if (p < S1CAP) {
                buf1[((size_t)b * 8 + shard) * S1CAP + p] = rec;
            } else {
                int sp = atomicAdd(&gspillc[b], 1);
                if (sp < SPCAP) spill[b * SPCAP + sp] = rec;
            }
        }
    }
}

// ---------------------------------------------------------------------------
// One block per bucket -> dense per-bucket CSR. Rows ceil4-padded AND the
// pad is zero-filled (dst=0,w=0) so aggregate needs no tail handling.
// cnt[node] = true degree (divisor).
// ---------------------------------------------------------------------------
__global__ __launch_bounds__(256) void build_csr(
    const int* __restrict__ gcur, const int2* __restrict__ buf1,
    const int* __restrict__ gspillc, const int2* __restrict__ spill,
    unsigned int* __restrict__ csr, int* __restrict__ rstart,
    int* __restrict__ cnt)
{
    __shared__ int lcnt[NPB];
    __shared__ int lstart[NPB];
    __shared__ int sa[256], sb[256];
    int tid = threadIdx.x, bkt = blockIdx.x;

    if (tid < NPB) lcnt[tid] = 0;
    __syncthreads();

    for (int sh = 0; sh < 9; ++sh) {
        int n; const int2* rp;
        if (sh < 8) {
            n = gcur[bkt * 8 + sh]; if (n > S1CAP) n = S1CAP;
            rp = buf1 + ((size_t)bkt * 8 + sh) * S1CAP;
        } else {
            n = gspillc[bkt]; if (n > SPCAP) n = SPCAP;
            rp = spill + (size_t)bkt * SPCAP;
        }
        for (int i = tid; i < n; i += 256)
            atomicAdd(&lcnt[rp[i].y], 1);
    }
    __syncthreads();

    // exclusive scan over ceil4(count): Hillis-Steele, 8 steps
    sa[tid] = (tid < NPB) ? ((lcnt[tid] + 3) & ~3) : 0;
    __syncthreads();
    int* s = sa; int* d = sb;
    for (int off = 1; off < 256; off <<= 1) {
        d[tid] = s[tid] + (tid >= off ? s[tid - off] : 0);
        __syncthreads();
        int* t = s; s = d; d = t;
    }
    if (tid < NPB) {
        int ex = (tid == 0) ? 0 : s[tid - 1];
        lstart[tid] = ex;
        int node = bkt * NPB + tid;
        if (node < NN) {
            rstart[node] = bkt * CSRCAP + ex;
            cnt[node] = lcnt[tid];
        }
    }
    __syncthreads();
    if (tid < NPB) lcnt[tid] = 0;   // reuse as placement cursor
    __syncthreads();

    for (int sh = 0; sh < 9; ++sh) {
        int n; const int2* rp;
        if (sh < 8) {
            n = gcur[bkt * 8 + sh]; if (n > S1CAP) n = S1CAP;
            rp = buf1 + ((size_t)bkt * 8 + sh) * S1CAP;
        } else {
            n = gspillc[bkt]; if (n > SPCAP) n = SPCAP;
            rp = spill + (size_t)bkt * SPCAP;
        }
        for (int i = tid; i < n; i += 256) {
            int2 r = rp[i];
            int pos = atomicAdd(&lcnt[r.y], 1);
            csr[bkt * CSRCAP + lstart[r.y] + pos] = (unsigned int)r.x;
        }
    }
    __syncthreads();

    // zero-fill the ceil4 pad (dst=0, w=0 -> contributes nothing)
    if (tid < NPB) {
        int c = lcnt[tid];
        int c4 = (c + 3) & ~3;
        for (int p = c; p < c4; ++p)
            csr[bkt * CSRCAP + lstart[tid] + p] = 0u;
    }
}

// ---------------------------------------------------------------------------
// Scatter-mean as gather, PAIRED: one wave per node; lanes 0-31 gather edge
// A's row as ushort2 (4B/lane), lanes 32-63 edge B's -> one instruction =
// 2 rows = full 256B transaction (R6 was 128B/edge). Halves combined by one
// __shfl_xor at the end. CSR rows are ceil4 zero-padded -> no tails.
// ---------------------------------------------------------------------------
__global__ __launch_bounds__(256) void aggregate(
    const ushort* __restrict__ feat, const int* __restrict__ rstart,
    const int* __restrict__ cnt, const unsigned int* __restrict__ csr,
    ushort* __restrict__ aggb)
{
    int node = (blockIdx.x * 256 + threadIdx.x) >> 6;   // grid exact: node < NN
    int lane = threadIdx.x & 63;
    int fl = lane & 31;
    int hi = lane >> 5;
    int n = cnt[node];
    int n4 = (n + 3) & ~3;
    const unsigned int* __restrict__ rp = csr + rstart[node];
    float a0 = 0.f, a1 = 0.f;

    int i = 0;
    for (; i + 8 <= n4; i += 8) {
        uint4 r0 = *(const uint4*)(rp + i);
        uint4 r1 = *(const uint4*)(rp + i + 4);
        unsigned int e0 = hi ? r0.y : r0.x;
        unsigned int e1 = hi ? r0.w : r0.z;
        unsigned int e2 = hi ? r1.y : r1.x;
        unsigned int e3 = hi ? r1.w : r1.z;
        ushort2 v0 = *(const ushort2*)&feat[(e0 & 0xFFFF) * DD + fl * 2];
        ushort2 v1 = *(const ushort2*)&feat[(e1 & 0xFFFF) * DD + fl * 2];
        ushort2 v2 = *(const ushort2*)&feat[(e2 & 0xFFFF) * DD + fl * 2];
        ushort2 v3 = *(const ushort2*)&feat[(e3 & 0xFFFF) * DD + fl * 2];
        float w0 = bf2f((unsigned short)(e0 >> 16));
        float w1 = bf2f((unsigned short)(e1 >> 16));
        float w2 = bf2f((unsigned short)(e2 >> 16));
        float w3 = bf2f((unsigned short)(e3 >> 16));
        a0 += w0 * bf2f(v0.x); a1 += w0 * bf2f(v0.y);
        a0 += w1 * bf2f(v1.x); a1 += w1 * bf2f(v1.y);
        a0 += w2 * bf2f(v2.x); a1 += w2 * bf2f(v2.y);
        a0 += w3 * bf2f(v3.x); a1 += w3 * bf2f(v3.y);
    }
    for (; i < n4; i += 4) {
        uint4 r0 = *(const uint4*)(rp + i);
        unsigned int e0 = hi ? r0.y : r0.x;
        unsigned int e1 = hi ? r0.w : r0.z;
        ushort2 v0 = *(const ushort2*)&feat[(e0 & 0xFFFF) * DD + fl * 2];
        ushort2 v1 = *(const ushort2*)&feat[(e1 & 0xFFFF) * DD + fl * 2];
        float w0 = bf2f((unsigned short)(e0 >> 16));
        float w1 = bf2f((unsigned short)(e1 >> 16));
        a0 += w0 * bf2f(v0.x); a1 += w0 * bf2f(v0.y);
        a0 += w1 * bf2f(v1.x); a1 += w1 * bf2f(v1.y);
    }

    a0 += __shfl_xor(a0, 32);
    a1 += __shfl_xor(a1, 32);

    if (lane < 32) {
        float dm = (float)(n > 1 ? n : 1);
        ushort2 o;
        o.x = f2bf(a0 / dm);
        o.y = f2bf(a1 / dm);
        *(ushort2*)&aggb[(size_t)node * DD + fl * 2] = o;
    }
}

// ---------------------------------------------------------------------------
// MFMA GEMM: out[n][j] = relu(b[j] + X[n][:]·Wb[j][0:64] + A[n][:]·Wb[j][64:128])
// mfma_f32_16x16x32_bf16, operands straight from global (no LDS):
//   A-frag: A[m=lane&15][k=quad*8+j] (measured m120) -> 16B/lane from act row
//   B-frag: B[k][n], n=lane&15, k=quad*8+j -> 16B/lane from Wb row n
//   C/D:    col=lane&15, row=quad*4+reg   (measured m89/m91)
// Block = 4 waves = 64 rows; wave w owns rows [blk*64+w*16, +16), all 64 cols.
// ---------------------------------------------------------------------------
__global__ __launch_bounds__(256) void sage_gemm_mfma(
    const ushort* __restrict__ X, const ushort* __restrict__ A,
    const ushort* __restrict__ Wb, const float* __restrict__ bias,
    float* __restrict__ out, ushort* __restrict__ outb)
{
    int tid = threadIdx.x;
    int wave = tid >> 6, lane = tid & 63;
    int quad = lane >> 4, l16 = lane & 15;
    int m0 = blockIdx.x * 64 + wave * 16;

    int arow = m0 + l16; if (arow >= NN) arow = NN - 1;   // clamp loads
    const ushort* __restrict__ ax = X + (size_t)arow * DD;
    const ushort* __restrict__ aa = A + (size_t)arow * DD;

    f32x4 acc[4];
#pragma unroll
    for (int t = 0; t < 4; ++t) acc[t] = (f32x4){0.f, 0.f, 0.f, 0.f};

#pragma unroll
    for (int ki = 0; ki < 4; ++ki) {
        const ushort* ap = (ki < 2) ? (ax + ki * 32 + quad * 8)
                                    : (aa + (ki - 2) * 32 + quad * 8);
        bf16x8 af = *(const bf16x8*)ap;
#pragma unroll
        for (int t = 0; t < 4; ++t) {
            const ushort* bp = Wb + (size_t)(t * 16 + l16) * 128 + ki * 32 + quad * 8;
            bf16x8 bfrag = *(const bf16x8*)bp;
            acc[t] = __builtin_amdgcn_mfma_f32_16x16x32_bf16(af, bfrag, acc[t], 0, 0, 0);
        }
    }

#pragma unroll
    for (int t = 0; t < 4; ++t) {
        int col = t * 16 + l16;
        float bv = bias[col];
#pragma unroll
        for (int r = 0; r < 4; ++r) {
            int grow = m0 + quad * 4 + r;
            if (grow < NN) {
                float v = fmaxf(acc[t][r] + bv, 0.f);
                if (out)  out[(size_t)grow * DD + col] = v;
                if (outb) outb[(size_t)grow * DD + col] = f2bf(v);
            }
        }
    }
}

// ---------------------------------------------------------------------------
extern "C" void kernel_launch(void* const* d_in, const int* in_sizes, int n_in,
                              void* d_out, int out_size, void* d_ws, size_t ws_size,
                              hipStream_t stream)
{
    const float* x  = (const float*)d_in[0];
    const int*   ei = (const int*)d_in[1];
    const float* ew = (const float*)d_in[2];
    const float* W1 = (const float*)d_in[3];
    const float* b1 = (const float*)d_in[4];
    const float* W2 = (const float*)d_in[5];
    const float* b2 = (const float*)d_in[6];
    float* out = (float*)d_out;

    // workspace layout, ~45.9 MB (16B-aligned offsets)
    char* ws = (char*)d_ws;
    int*          gcur    = (int*)ws;                          //      8,192 B
    int*          gspillc = (int*)(ws + 8192);                 //      1,024 B
    int2*         buf1    = (int2*)(ws + 16384);               // 16,777,216 B
    int2*         spill   = (int2*)(ws + 16793600);            //  1,048,576 B
    unsigned int* csr     = (unsigned int*)(ws + 17842176);    //  8,388,608 B
    int*          rstart  = (int*)(ws + 26230784);             //    200,704 B
    int*          cnt     = (int*)(ws + 26431488);             //    200,704 B
    ushort*       xb      = (ushort*)(ws + 26632192);          //  6,400,000 B
    ushort*       aggb    = (ushort*)(ws + 33032192);          //  6,400,000 B
    ushort*       h1b     = (ushort*)(ws + 39432192);          //  6,400,000 B
    ushort*       W1b     = (ushort*)(ws + 45832192);          //     16,384 B
    ushort*       W2b     = (ushort*)(ws + 45848576);          //     16,384 B

    hipMemsetAsync(gcur, 0, 9216, stream);   // gcur + gspillc

    cast_bf16<<<(NN * DD / 4) / 256, 256, 0, stream>>>(x, xb, NN * DD / 4);
    cast_w<<<16, 256, 0, stream>>>(W1, W2, W1b, W2b);
    bin_lds<<<NBLK, 256, 0, stream>>>(ei, ew, gcur, gspillc, buf1, spill);
    build_csr<<<NBKT, 256, 0, stream>>>(gcur, buf1, gspillc, spill, csr, rstart, cnt);

    // layer 1
    aggregate<<<(NN * 64) / 256, 256, 0, stream>>>(xb, rstart, cnt, csr, aggb);
    sage_gemm_mfma<<<(NN + 63) / 64, 256, 0, stream>>>(xb, aggb, W1b, b1, nullptr, h1b);

    // layer 2 (same graph, reuse CSR)
    aggregate<<<(NN * 64) / 256, 256, 0, stream>>>(h1b, rstart, cnt, csr, aggb);
    sage_gemm_mfma<<<(NN + 63) / 64, 256, 0, stream>>>(h1b, aggb, W2b, b2, out, nullptr);
}

// Round 8
// 216.120 us; speedup vs baseline: 2.0468x; 1.0716x over previous
//
#include <hip/hip_runtime.h>

#define NN 50000
#define NE 1600000
#define DD 64
#define NPB 196          // nodes per bucket
#define NBKT 256         // buckets (NPB*NBKT = 50176 >= NN)
#define CHUNK 2500       // edges per bin block (640 blocks * 2500 = NE)
#define NBLK 640
#define SLOT 24          // LDS records per bucket: lambda=9.77, +4.5 sigma
#define S1CAP 1024       // per-(bucket,shard) region: lambda=781, +8.7 sigma
#define SPCAP 512        // per-bucket global spill region
#define CSRCAP 8192      // per-bucket CSR capacity (R4-proven)

typedef __attribute__((ext_vector_type(8))) short bf16x8;   // 8 bf16 = 4 VGPR
typedef __attribute__((ext_vector_type(4))) float f32x4;

static __device__ __forceinline__ unsigned short f2bf(float f) {
    unsigned int u = __float_as_uint(f);
    unsigned int r = (u + 0x7FFFu + ((u >> 16) & 1u)) >> 16;   // RNE
    return (unsigned short)r;
}
static __device__ __forceinline__ float bf2f(unsigned short h) {
    return __uint_as_float((unsigned int)h << 16);
}

// ---------------------------------------------------------------------------
// prep: fused x->bf16 cast (blocks 0..3124), W1/W2->bf16 (blocks 3125..3140),
// and gcur/gspillc zeroing (block 3141). Saves 2 dispatches vs R7.
// ---------------------------------------------------------------------------
__global__ __launch_bounds__(256) void prep(
    const float* __restrict__ x, ushort* __restrict__ xb,
    const float* __restrict__ W1, const float* __restrict__ W2,
    ushort* __restrict__ W1b, ushort* __restrict__ W2b,
    int* __restrict__ gcur)
{
    int b = blockIdx.x, tid = threadIdx.x;
    if (b < 3125) {                        // 3125*256 = 800000 = NN*DD/4
        int i = b * 256 + tid;
        float4 v = ((const float4*)x)[i];
        ushort4 o;
        o.x = f2bf(v.x); o.y = f2bf(v.y); o.z = f2bf(v.z); o.w = f2bf(v.w);
        ((ushort4*)xb)[i] = o;
    } else if (b < 3141) {                 // 16*256 = 4096 float4 groups
        int i = (b - 3125) * 256 + tid;
        const float* src = (i < 2048) ? W1 : W2;
        ushort* dst = (i < 2048) ? W1b : W2b;
        int j = i & 2047;
        float4 v = ((const float4*)src)[j];
        ushort4 o;
        o.x = f2bf(v.x); o.y = f2bf(v.y); o.z = f2bf(v.z); o.w = f2bf(v.w);
        ((ushort4*)dst)[j] = o;
    } else {                               // zero gcur (2048) + gspillc (256)
        for (int i = tid; i < 2304; i += 256) gcur[i] = 0;
    }
}

// ---------------------------------------------------------------------------
// LDS-staged binning (R6-proven: one global atomic per (block,bucket), not
// per edge). Burst-flush into (bucket, blockIdx&7) sequential regions.
// Record: .x = dst(16) | w_bf16<<16, .y = node-within-bucket.
// ---------------------------------------------------------------------------
__global__ __launch_bounds__(256) void bin_lds(
    const int* __restrict__ ei, const float* __restrict__ ew,
    int* __restrict__ gcur, int* __restrict__ gspillc,
    int2* __restrict__ buf1, int2* __restrict__ spill)
{
    __shared__ int2 slot[NBKT * SLOT];   // 48 KB
    __shared__ int  lcnt[NBKT];
    __shared__ int  lbase[NBKT];
    int tid = threadIdx.x;
    int shard = blockIdx.x & 7;

    for (int b = tid; b < NBKT; b += 256) lcnt[b] = 0;
    __syncthreads();

    int e0 = blockIdx.x * CHUNK;
    for (int i = tid; i < CHUNK; i += 256) {
        int e = e0 + i;
        int s = ei[e];           // edge_index[0] = src (scatter target)
        int d = ei[NE + e];      // edge_index[1] = dst (gather source)
        float w = ew[e];
        int bkt = s / NPB;
        int sloc = s - bkt * NPB;
        int2 rec = make_int2(d | ((int)f2bf(w) << 16), sloc);
        int pos = atomicAdd(&lcnt[bkt], 1);
        if (pos < SLOT) {
            slot[bkt * SLOT + pos] = rec;
        } else {
            int sp = atomicAdd(&gspillc[bkt], 1);
            if (sp < SPCAP) spill[bkt * SPCAP + sp] = rec;
        }
    }
    __syncthreads();

    // one global reservation per (block,bucket); tid==bucket (256==NBKT)
    {
        int b = tid;
        int n = lcnt[b]; if (n > SLOT) n = SLOT;
        lcnt[b] = n;
        lbase[b] = (n > 0) ? atomicAdd(&gcur[b * 8 + shard], n) : 0;
    }
    __syncthreads();

    // wave-cooperative burst copy: wave w flushes buckets w*64..+63
    int wave = tid >> 6, lane = tid & 63;
    for (int j = 0; j < NBKT / 4; ++j) {
        int b = wave * (NBKT / 4) + j;
        int n = lcnt[b];
        int base = lbase[b];
        for (int i = lane; i < n; i += 64) {
            int p = base + i;
            int2 rec = slot[b * SLOT + i];
            if (p < S1CAP) {
                buf1[((size_t)b * 8 + shard) * S1CAP + p] = rec;
            } else {
                int sp = atomicAdd(&gspillc[b], 1);
                if (sp < SPCAP) spill[b * SPCAP + sp] = rec;
            }
        }
    }
}

// ---------------------------------------------------------------------------
// One block per bucket -> dense per-bucket CSR. Rows ceil4-padded AND the
// pad is zero-filled (dst=0,w=0) so aggregate needs no tail handling.
// cnt[node] = true degree (divisor).
// ---------------------------------------------------------------------------
__global__ __launch_bounds__(256) void build_csr(
    const int* __restrict__ gcur, const int2* __restrict__ buf1,
    const int* __restrict__ gspillc, const int2* __restrict__ spill,
    unsigned int* __restrict__ csr, int* __restrict__ rstart,
    int* __restrict__ cnt)
{
    __shared__ int lcnt[NPB];
    __shared__ int lstart[NPB];
    __shared__ int sa[256], sb[256];
    int tid = threadIdx.x, bkt = blockIdx.x;

    if (tid < NPB) lcnt[tid] = 0;
    __syncthreads();

    for (int sh = 0; sh < 9; ++sh) {
        int n; const int2* rp;
        if (sh < 8) {
            n = gcur[bkt * 8 + sh]; if (n > S1CAP) n = S1CAP;
            rp = buf1 + ((size_t)bkt * 8 + sh) * S1CAP;
        } else {
            n = gspillc[bkt]; if (n > SPCAP) n = SPCAP;
            rp = spill + (size_t)bkt * SPCAP;
        }
        for (int i = tid; i < n; i += 256)
            atomicAdd(&lcnt[rp[i].y], 1);
    }
    __syncthreads();

    // exclusive scan over ceil4(count): Hillis-Steele, 8 steps
    sa[tid] = (tid < NPB) ? ((lcnt[tid] + 3) & ~3) : 0;
    __syncthreads();
    int* s = sa; int* d = sb;
    for (int off = 1; off < 256; off <<= 1) {
        d[tid] = s[tid] + (tid >= off ? s[tid - off] : 0);
        __syncthreads();
        int* t = s; s = d; d = t;
    }
    if (tid < NPB) {
        int ex = (tid == 0) ? 0 : s[tid - 1];
        lstart[tid] = ex;
        int node = bkt * NPB + tid;
        if (node < NN) {
            rstart[node] = bkt * CSRCAP + ex;
            cnt[node] = lcnt[tid];
        }
    }
    __syncthreads();
    if (tid < NPB) lcnt[tid] = 0;   // reuse as placement cursor
    __syncthreads();

    for (int sh = 0; sh < 9; ++sh) {
        int n; const int2* rp;
        if (sh < 8) {
            n = gcur[bkt * 8 + sh]; if (n > S1CAP) n = S1CAP;
            rp = buf1 + ((size_t)bkt * 8 + sh) * S1CAP;
        } else {
            n = gspillc[bkt]; if (n > SPCAP) n = SPCAP;
            rp = spill + (size_t)bkt * SPCAP;
        }
        for (int i = tid; i < n; i += 256) {
            int2 r = rp[i];
            int pos = atomicAdd(&lcnt[r.y], 1);
            csr[bkt * CSRCAP + lstart[r.y] + pos] = (unsigned int)r.x;
        }
    }
    __syncthreads();

    // zero-fill the ceil4 pad (dst=0, w=0 -> contributes nothing)
    if (tid < NPB) {
        int c = lcnt[tid];
        int c4 = (c + 3) & ~3;
        for (int p = c; p < c4; ++p)
            csr[bkt * CSRCAP + lstart[tid] + p] = 0u;
    }
}

// ---------------------------------------------------------------------------
// Scatter-mean as gather, PAIRED + DEEP: one wave per node; lanes 0-31 own
// even records' rows (ushort2 = 4B/lane), lanes 32-63 odd -> each gather
// instruction covers 2 rows (256B). R8: 16 records/iter = 8 gathers in
// flight per wave (R7's 4 left the memory system half-fed: ~32KB/CU in
// flight vs ~40KB needed at ~300cyc). Halves combined via one __shfl_xor.
// ---------------------------------------------------------------------------
__global__ __launch_bounds__(256) void aggregate(
    const ushort* __restrict__ feat, const int* __restrict__ rstart,
    const int* __restrict__ cnt, const unsigned int* __restrict__ csr,
    ushort* __restrict__ aggb)
{
    int node = (blockIdx.x * 256 + threadIdx.x) >> 6;   // grid exact: node < NN
    int lane = threadIdx.x & 63;
    int fl = lane & 31;
    int hi = lane >> 5;
    int n = cnt[node];
    int n4 = (n + 3) & ~3;
    const unsigned int* __restrict__ rp = csr + rstart[node];
    float a0 = 0.f, a1 = 0.f;

    int i = 0;
    for (; i + 16 <= n4; i += 16) {
        uint4 r0 = *(const uint4*)(rp + i);
        uint4 r1 = *(const uint4*)(rp + i + 4);
        uint4 r2 = *(const uint4*)(rp + i + 8);
        uint4 r3 = *(const uint4*)(rp + i + 12);
        unsigned int e0 = hi ? r0.y : r0.x;
        unsigned int e1 = hi ? r0.w : r0.z;
        unsigned int e2 = hi ? r1.y : r1.x;
        unsigned int e3 = hi ? r1.w : r1.z;
        unsigned int e4 = hi ? r2.y : r2.x;
        unsigned int e5 = hi ? r2.w : r2.z;
        unsigned int e6 = hi ? r3.y : r3.x;
        unsigned int e7 = hi ? r3.w : r3.z;
        ushort2 v0 = *(const ushort2*)&feat[(e0 & 0xFFFF) * DD + fl * 2];
        ushort2 v1 = *(const ushort2*)&feat[(e1 & 0xFFFF) * DD + fl * 2];
        ushort2 v2 = *(const ushort2*)&feat[(e2 & 0xFFFF) * DD + fl * 2];
        ushort2 v3 = *(const ushort2*)&feat[(e3 & 0xFFFF) * DD + fl * 2];
        ushort2 v4 = *(const ushort2*)&feat[(e4 & 0xFFFF) * DD + fl * 2];
        ushort2 v5 = *(const ushort2*)&feat[(e5 & 0xFFFF) * DD + fl * 2];
        ushort2 v6 = *(const ushort2*)&feat[(e6 & 0xFFFF) * DD + fl * 2];
        ushort2 v7 = *(const ushort2*)&feat[(e7 & 0xFFFF) * DD + fl * 2];
        float w0 = bf2f((unsigned short)(e0 >> 16));
        float w1 = bf2f((unsigned short)(e1 >> 16));
        float w2 = bf2f((unsigned short)(e2 >> 16));
        float w3 = bf2f((unsigned short)(e3 >> 16));
        float w4 = bf2f((unsigned short)(e4 >> 16));
        float w5 = bf2f((unsigned short)(e5 >> 16));
        float w6 = bf2f((unsigned short)(e6 >> 16));
        float w7 = bf2f((unsigned short)(e7 >> 16));
        a0 += w0 * bf2f(v0.x); a1 += w0 * bf2f(v0.y);
        a0 += w1 * bf2f(v1.x); a1 += w1 * bf2f(v1.y);
        a0 += w2 * bf2f(v2.x); a1 += w2 * bf2f(v2.y);
        a0 += w3 * bf2f(v3.x); a1 += w3 * bf2f(v3.y);
        a0 += w4 * bf2f(v4.x); a1 += w4 * bf2f(v4.y);
        a0 += w5 * bf2f(v5.x); a1 += w5 * bf2f(v5.y);
        a0 += w6 * bf2f(v6.x); a1 += w6 * bf2f(v6.y);
        a0 += w7 * bf2f(v7.x); a1 += w7 * bf2f(v7.y);
    }
    for (; i + 8 <= n4; i += 8) {
        uint4 r0 = *(const uint4*)(rp + i);
        uint4 r1 = *(const uint4*)(rp + i + 4);
        unsigned int e0 = hi ? r0.y : r0.x;
        unsigned int e1 = hi ? r0.w : r0.z;
        unsigned int e2 = hi ? r1.y : r1.x;
        unsigned int e3 = hi ? r1.w : r1.z;
        ushort2 v0 = *(const ushort2*)&feat[(e0 & 0xFFFF) * DD + fl * 2];
        ushort2 v1 = *(const ushort2*)&feat[(e1 & 0xFFFF) * DD + fl * 2];
        ushort2 v2 = *(const ushort2*)&feat[(e2 & 0xFFFF) * DD + fl * 2];
        ushort2 v3 = *(const ushort2*)&feat[(e3 & 0xFFFF) * DD + fl * 2];
        float w0 = bf2f((unsigned short)(e0 >> 16));
        float w1 = bf2f((unsigned short)(e1 >> 16));
        float w2 = bf2f((unsigned short)(e2 >> 16));
        float w3 = bf2f((unsigned short)(e3 >> 16));
        a0 += w0 * bf2f(v0.x); a1 += w0 * bf2f(v0.y);
        a0 += w1 * bf2f(v1.x); a1 += w1 * bf2f(v1.y);
        a0 += w2 * bf2f(v2.x); a1 += w2 * bf2f(v2.y);
        a0 += w3 * bf2f(v3.x); a1 += w3 * bf2f(v3.y);
    }
    for (; i < n4; i += 4) {
        uint4 r0 = *(const uint4*)(rp + i);
        unsigned int e0 = hi ? r0.y : r0.x;
        unsigned int e1 = hi ? r0.w : r0.z;
        ushort2 v0 = *(const ushort2*)&feat[(e0 & 0xFFFF) * DD + fl * 2];
        ushort2 v1 = *(const ushort2*)&feat[(e1 & 0xFFFF) * DD + fl * 2];
        float w0 = bf2f((unsigned short)(e0 >> 16));
        float w1 = bf2f((unsigned short)(e1 >> 16));
        a0 += w0 * bf2f(v0.x); a1 += w0 * bf2f(v0.y);
        a0 += w1 * bf2f(v1.x); a1 += w1 * bf2f(v1.y);
    }

    a0 += __shfl_xor(a0, 32);
    a1 += __shfl_xor(a1, 32);

    if (lane < 32) {
        float dm = (float)(n > 1 ? n : 1);
        ushort2 o;
        o.x = f2bf(a0 / dm);
        o.y = f2bf(a1 / dm);
        *(ushort2*)&aggb[(size_t)node * DD + fl * 2] = o;
    }
}

// ---------------------------------------------------------------------------
// MFMA GEMM: out[n][j] = relu(b[j] + X[n][:]·Wb[j][0:64] + A[n][:]·Wb[j][64:128])
// mfma_f32_16x16x32_bf16, operands straight from global (R7-verified layouts).
// Block = 4 waves = 64 rows; wave w owns rows [blk*64+w*16, +16), all 64 cols.
// ---------------------------------------------------------------------------
__global__ __launch_bounds__(256) void sage_gemm_mfma(
    const ushort* __restrict__ X, const ushort* __restrict__ A,
    const ushort* __restrict__ Wb, const float* __restrict__ bias,
    float* __restrict__ out, ushort* __restrict__ outb)
{
    int tid = threadIdx.x;
    int wave = tid >> 6, lane = tid & 63;
    int quad = lane >> 4, l16 = lane & 15;
    int m0 = blockIdx.x * 64 + wave * 16;

    int arow = m0 + l16; if (arow >= NN) arow = NN - 1;   // clamp loads
    const ushort* __restrict__ ax = X + (size_t)arow * DD;
    const ushort* __restrict__ aa = A + (size_t)arow * DD;

    f32x4 acc[4];
#pragma unroll
    for (int t = 0; t < 4; ++t) acc[t] = (f32x4){0.f, 0.f, 0.f, 0.f};

#pragma unroll
    for (int ki = 0; ki < 4; ++ki) {
        const ushort* ap = (ki < 2) ? (ax + ki * 32 + quad * 8)
                                    : (aa + (ki - 2) * 32 + quad * 8);
        bf16x8 af = *(const bf16x8*)ap;
#pragma unroll
        for (int t = 0; t < 4; ++t) {
            const ushort* bp = Wb + (size_t)(t * 16 + l16) * 128 + ki * 32 + quad * 8;
            bf16x8 bfrag = *(const bf16x8*)bp;
            acc[t] = __builtin_amdgcn_mfma_f32_16x16x32_bf16(af, bfrag, acc[t], 0, 0, 0);
        }
    }

#pragma unroll
    for (int t = 0; t < 4; ++t) {
        int col = t * 16 + l16;
        float bv = bias[col];
#pragma unroll
        for (int r = 0; r < 4; ++r) {
            int grow = m0 + quad * 4 + r;
            if (grow < NN) {
                float v = fmaxf(acc[t][r] + bv, 0.f);
                if (out)  out[(size_t)grow * DD + col] = v;
                if (outb) outb[(size_t)grow * DD + col] = f2bf(v);
            }
        }
    }
}

// ---------------------------------------------------------------------------
extern "C" void kernel_launch(void* const* d_in, const int* in_sizes, int n_in,
                              void* d_out, int out_size, void* d_ws, size_t ws_size,
                              hipStream_t stream)
{
    const float* x  = (const float*)d_in[0];
    const int*   ei = (const int*)d_in[1];
    const float* ew = (const float*)d_in[2];
    const float* W1 = (const float*)d_in[3];
    const float* b1 = (const float*)d_in[4];
    const float* W2 = (const float*)d_in[5];
    const float* b2 = (const float*)d_in[6];
    float* out = (float*)d_out;

    // workspace layout, ~45.9 MB (16B-aligned offsets)
    char* ws = (char*)d_ws;
    int*          gcur    = (int*)ws;                          //      8,192 B
    int*          gspillc = (int*)(ws + 8192);                 //      1,024 B
    int2*         buf1    = (int2*)(ws + 16384);               // 16,777,216 B
    int2*         spill   = (int2*)(ws + 16793600);            //  1,048,576 B
    unsigned int* csr     = (unsigned int*)(ws + 17842176);    //  8,388,608 B
    int*          rstart  = (int*)(ws + 26230784);             //    200,704 B
    int*          cnt     = (int*)(ws + 26431488);             //    200,704 B
    ushort*       xb      = (ushort*)(ws + 26632192);          //  6,400,000 B
    ushort*       aggb    = (ushort*)(ws + 33032192);          //  6,400,000 B
    ushort*       h1b     = (ushort*)(ws + 39432192);          //  6,400,000 B
    ushort*       W1b     = (ushort*)(ws + 45832192);          //     16,384 B
    ushort*       W2b     = (ushort*)(ws + 45848576);          //     16,384 B

    prep<<<3142, 256, 0, stream>>>(x, xb, W1, W2, W1b, W2b, gcur);
    bin_lds<<<NBLK, 256, 0, stream>>>(ei, ew, gcur, gspillc, buf1, spill);
    build_csr<<<NBKT, 256, 0, stream>>>(gcur, buf1, gspillc, spill, csr, rstart, cnt);

    // layer 1
    aggregate<<<(NN * 64) / 256, 256, 0, stream>>>(xb, rstart, cnt, csr, aggb);
    sage_gemm_mfma<<<(NN + 63) / 64, 256, 0, stream>>>(xb, aggb, W1b, b1, nullptr, h1b);

    // layer 2 (same graph, reuse CSR)
    aggregate<<<(NN * 64) / 256, 256, 0, stream>>>(h1b, rstart, cnt, csr, aggb);
    sage_gemm_mfma<<<(NN + 63) / 64, 256, 0, stream>>>(h1b, aggb, W2b, b2, out, nullptr);
}